// Round 1
// baseline (486.643 us; speedup 1.0000x reference)
//
#include <hip/hip_runtime.h>

// Problem constants
#define NB     16
#define LATD   512
#define FIN_C  128
#define FOUT_C 128
#define KK     3
#define HW     64
#define KSZ    147456      // FOUT*FIN*K*K
#define NROWS  147584      // KSZ + FOUT (bias rows)

// ---------------------------------------------------------------------------
// Kernel 1: hyper-network GEMM.  ks[b][n] = dot(lat[b], W[n]) + bvec[n]
// Output layout: kt[b][fi][tap][fo]  (tap = ky*3+kx), bias_ws[b][fo].
// One thread per destination column d (destination-major => coalesced writes).
// ---------------------------------------------------------------------------
__global__ __launch_bounds__(256) void hyper_gemm(
    const float* __restrict__ lat, const float* __restrict__ W,
    const float* __restrict__ bvec, float* __restrict__ kt,
    float* __restrict__ bias_ws) {
  int d = blockIdx.x * 256 + threadIdx.x;
  if (d >= NROWS) return;

  long n;
  int fo;
  bool isBias = (d >= KSZ);
  if (!isBias) {
    fo = d & 127;              // kt fastest dim = fo
    int rest = d >> 7;         // fi*9 + tap
    int tap = rest % 9;
    int fi  = rest / 9;
    // reference row index: n = ((fo*FIN + fi)*3 + ky)*3 + kx
    n = (long)fo * (FIN_C * KK * KK) + fi * (KK * KK) + tap;
  } else {
    fo = d - KSZ;
    n = KSZ + fo;
  }

  const float* wrow = W + n * LATD;
  float bv = bvec[n];
  float acc[NB];
#pragma unroll
  for (int b = 0; b < NB; ++b) acc[b] = bv;

#pragma unroll 2
  for (int k = 0; k < LATD; k += 4) {
    float4 wv = *reinterpret_cast<const float4*>(wrow + k);
#pragma unroll
    for (int b = 0; b < NB; ++b) {
      // lat indices are workgroup-uniform -> scalar loads (K$-resident, 32 KB)
      acc[b] += wv.x * lat[b * LATD + k]
              + wv.y * lat[b * LATD + k + 1]
              + wv.z * lat[b * LATD + k + 2]
              + wv.w * lat[b * LATD + k + 3];
    }
  }

  if (!isBias) {
#pragma unroll
    for (int b = 0; b < NB; ++b)
      kt[(long)b * KSZ + d] = acc[b];          // coalesced: consecutive d
  } else {
#pragma unroll
    for (int b = 0; b < NB; ++b)
      bias_ws[b * FOUT_C + fo] = acc[b];
  }
}

// ---------------------------------------------------------------------------
// Kernel 2: per-sample 3x3 conv, pad=1.
// Block = 1 wave (64 threads). grid = (h=64, b=16, foq=4).
// lane = w  (coalesced x loads / out stores)
// Each lane accumulates 32 fo outputs; weights are wave-uniform -> s_load.
// blockIdx.z carries the fo-quarter so weight addresses are PROVABLY uniform.
// ---------------------------------------------------------------------------
__global__ __launch_bounds__(64) void dyn_conv(
    const float* __restrict__ x, const float* __restrict__ kt,
    const float* __restrict__ bias_ws, float* __restrict__ out) {
  const int h   = blockIdx.x;        // 0..63
  const int b   = blockIdx.y;        // 0..15
  const int fo0 = blockIdx.z * 32;   // fo quarter base (uniform!)
  const int w   = threadIdx.x;       // 0..63

  const float* xb  = x + (long)b * FIN_C * (HW * HW);
  const float* ktb = kt + (long)b * KSZ;
  const float* bb  = bias_ws + b * FOUT_C + fo0;

  float acc[32];
#pragma unroll
  for (int j = 0; j < 32; ++j) acc[j] = bb[j];   // uniform scalar loads

  for (int fi = 0; fi < FIN_C; ++fi) {
    // --- load the 3x3 input window for this lane's column (per-lane, coalesced)
    float xv[9];
    const float* xr = xb + fi * (HW * HW);
#pragma unroll
    for (int ky = 0; ky < 3; ++ky) {
      int hy = h + ky - 1;
      bool vr = (hy >= 0) && (hy < HW);
      const float* row = xr + hy * HW;
      xv[ky * 3 + 0] = (vr && w > 0)  ? row[w - 1] : 0.f;
      xv[ky * 3 + 1] = vr             ? row[w]     : 0.f;
      xv[ky * 3 + 2] = (vr && w < 63) ? row[w + 1] : 0.f;
    }
    // --- weights: kt[b][fi][tap][fo0..fo0+31], uniform -> s_load_dwordx16 x2
    const float* wt = ktb + fi * (KK * KK * FOUT_C) + fo0;
#pragma unroll
    for (int t = 0; t < 9; ++t) {
#pragma unroll
      for (int j = 0; j < 32; ++j) {
        acc[j] += xv[t] * wt[t * FOUT_C + j];    // v += v * s : 1 SGPR operand
      }
    }
  }

  float* ob = out + (((long)b * FOUT_C + fo0) * HW + h) * HW + w;
#pragma unroll
  for (int j = 0; j < 32; ++j) ob[(long)j * (HW * HW)] = acc[j];
}

// ---------------------------------------------------------------------------
extern "C" void kernel_launch(void* const* d_in, const int* in_sizes, int n_in,
                              void* d_out, int out_size, void* d_ws, size_t ws_size,
                              hipStream_t stream) {
  const float* x   = (const float*)d_in[0];   // (16,128,64,64)
  const float* lat = (const float*)d_in[1];   // (16,512)
  const float* W   = (const float*)d_in[2];   // (147584,512)
  const float* bv  = (const float*)d_in[3];   // (147584,)
  float* out = (float*)d_out;                 // (16,128,64,64) fp32

  float* kt      = (float*)d_ws;                    // 16*147456 floats (9.4 MB)
  float* bias_ws = kt + (size_t)NB * KSZ;           // 16*128 floats

  hyper_gemm<<<dim3((NROWS + 255) / 256), dim3(256), 0, stream>>>(
      lat, W, bv, kt, bias_ws);
  dyn_conv<<<dim3(HW, NB, 4), dim3(64), 0, stream>>>(x, kt, bias_ws, out);
}

// Round 2
// 186.112 us; speedup vs baseline: 2.6148x; 2.6148x over previous
//
#include <hip/hip_runtime.h>

// Problem constants
#define NB     16
#define LATD   512
#define FIN_C  128
#define FOUT_C 128
#define KK     3
#define HW     64
#define KSZ    147456      // FOUT*FIN*K*K
#define NROWS  147584      // KSZ + FOUT (bias rows)

// padded channel-last x: [b][66][66][128]
#define XPAD   66
#define XROW_E (XPAD * FIN_C)            // 8448 elems per padded row
#define XT_BE  ((size_t)XPAD * XPAD * FIN_C)  // 557568 elems per b

// workspace layout (bytes)
#define AFH_OFF  ((size_t)0)
#define AF_BYTES ((size_t)NB * KSZ * 2)          // 4,718,592
#define AFL_OFF  (AFH_OFF + AF_BYTES)
#define XTH_OFF  (AFL_OFF + AF_BYTES)            // 9,437,184
#define XT_BYTES ((size_t)NB * XT_BE * 2)        // 17,842,176
#define XTL_OFF  (XTH_OFF + XT_BYTES)
#define BIAS_OFF (XTL_OFF + XT_BYTES)            // 45,121,536
#define WS_NEED  (BIAS_OFF + (size_t)NB * FOUT_C * 4)

typedef __attribute__((ext_vector_type(8))) short bf16x8;
typedef __attribute__((ext_vector_type(4))) float f32x4;

#define GLOAD16(gp, lp)                                                        \
  __builtin_amdgcn_global_load_lds(                                            \
      (const __attribute__((address_space(1))) void*)(gp),                     \
      (__attribute__((address_space(3))) void*)(lp), 16, 0, 0)

__device__ __forceinline__ unsigned short f2bf(float f) {
  unsigned u = __builtin_bit_cast(unsigned, f);
  u += 0x7fffu + ((u >> 16) & 1u);       // RNE
  return (unsigned short)(u >> 16);
}
__device__ __forceinline__ float bf2f(unsigned short h) {
  return __builtin_bit_cast(float, ((unsigned)h) << 16);
}

// ---------------------------------------------------------------------------
// Kernel 1: hyper GEMM.  ks[n][b] -> kern written as bf16 hi/lo in MFMA
// A-fragment order: Af[b][t][fib][mt][lane][e] ; bias rows -> fp32 bias_ws.
// lat (32 KB) staged in LDS to kill scalar-cache thrash.
// ---------------------------------------------------------------------------
__global__ __launch_bounds__(256) void hyper_gemm2(
    const float* __restrict__ lat, const float* __restrict__ W,
    const float* __restrict__ bvec, unsigned short* __restrict__ Afh,
    unsigned short* __restrict__ Afl, float* __restrict__ bias_ws) {
  __shared__ float lds_lat[NB * LATD];   // 32 KB
  const int tid = threadIdx.x;
#pragma unroll
  for (int r = 0; r < 8; ++r) {
    int i = tid + r * 256;
    *(float4*)&lds_lat[i * 4] = *(const float4*)(lat + i * 4);
  }
  __syncthreads();

  if (blockIdx.x == 576) {               // bias rows
    if (tid >= FOUT_C) return;
    int n = KSZ + tid;
    const float4* w4 = (const float4*)(W + (size_t)n * LATD);
    float4 a4[NB] = {};
#pragma unroll 2
    for (int k4 = 0; k4 < LATD / 4; ++k4) {
      float4 wv = w4[k4];
#pragma unroll
      for (int b = 0; b < NB; ++b) {
        float4 lv = *(const float4*)&lds_lat[b * LATD + k4 * 4];
        a4[b].x += wv.x * lv.x; a4[b].y += wv.y * lv.y;
        a4[b].z += wv.z * lv.z; a4[b].w += wv.w * lv.w;
      }
    }
    float bv = bvec[n];
#pragma unroll
    for (int b = 0; b < NB; ++b)
      bias_ws[b * FOUT_C + tid] = a4[b].x + a4[b].y + a4[b].z + a4[b].w + bv;
    return;
  }

  const int d = blockIdx.x * 256 + tid;  // Af linear index
  const int e = d & 7, l = (d >> 3) & 63, mt = (d >> 9) & 7;
  const int fib = (d >> 12) & 3, t = d >> 14;
  const int fo = mt * 16 + (l & 15);
  const int fi = fib * 32 + (l >> 4) * 8 + e;
  const int n = fo * (FIN_C * KK * KK) + fi * (KK * KK) + t;

  const float4* w4 = (const float4*)(W + (size_t)n * LATD);
  float4 a4[NB] = {};
#pragma unroll 2
  for (int k4 = 0; k4 < LATD / 4; ++k4) {
    float4 wv = w4[k4];
#pragma unroll
    for (int b = 0; b < NB; ++b) {
      float4 lv = *(const float4*)&lds_lat[b * LATD + k4 * 4];
      a4[b].x += wv.x * lv.x; a4[b].y += wv.y * lv.y;
      a4[b].z += wv.z * lv.z; a4[b].w += wv.w * lv.w;
    }
  }
  float bv = bvec[n];
#pragma unroll
  for (int b = 0; b < NB; ++b) {
    float ks = a4[b].x + a4[b].y + a4[b].z + a4[b].w + bv;
    unsigned short h = f2bf(ks);
    unsigned short lo = f2bf(ks - bf2f(h));
    Afh[(size_t)b * KSZ + d] = h;
    Afl[(size_t)b * KSZ + d] = lo;
  }
}

// ---------------------------------------------------------------------------
// Kernel 2: prepass — x[b][fi][y][w] fp32  ->  padded channel-last bf16 hi/lo
// xT[b][y+1][x+1][fi], borders zero.  LDS tile transpose per (b, y-row).
// ---------------------------------------------------------------------------
__global__ __launch_bounds__(256) void prepass(
    const float* __restrict__ x, unsigned short* __restrict__ xTh,
    unsigned short* __restrict__ xTl) {
  __shared__ float tile[FIN_C * 65];     // pitch 65 to break bank conflicts
  const int y = blockIdx.x;              // 0..65 padded row
  const int b = blockIdx.y;
  const int tid = threadIdx.x;
  const bool interior = (y >= 1 && y <= HW);

  if (interior) {
    int yy = y - 1;
#pragma unroll
    for (int r = 0; r < 8; ++r) {
      int idx = tid + r * 256;           // 0..2047
      int fi = idx >> 4, q = idx & 15;
      float4 v = *(const float4*)(x + ((size_t)(b * FIN_C + fi) * (HW * HW)) +
                                  yy * HW + q * 4);
      float* dst = &tile[fi * 65 + q * 4];
      dst[0] = v.x; dst[1] = v.y; dst[2] = v.z; dst[3] = v.w;
    }
  }
  __syncthreads();

  for (int r = 0; r < 5; ++r) {
    int gg = tid + r * 256;              // granule: (x 0..65) x (fi8 0..15)
    if (gg >= XPAD * 16) break;
    int xc = gg >> 4, f8 = gg & 15;
    bf16x8 hv = {}, lv = {};
    if (interior && xc >= 1 && xc <= HW) {
#pragma unroll
      for (int e2 = 0; e2 < 8; ++e2) {
        float f = tile[(f8 * 8 + e2) * 65 + (xc - 1)];
        unsigned short h = f2bf(f);
        hv[e2] = (short)h;
        lv[e2] = (short)f2bf(f - bf2f(h));
      }
    }
    size_t off = ((size_t)b * XPAD * XPAD + (size_t)y * XPAD + xc) * FIN_C + f8 * 8;
    *(bf16x8*)(xTh + off) = hv;
    *(bf16x8*)(xTl + off) = lv;
  }
}

// ---------------------------------------------------------------------------
// Kernel 3: MFMA conv.  Per (b, px-tile of 128): C[128 fo][128 px] =
// sum over t(9) x fib(4) of A(kern frag) * B(x slice), 3-way bf16 split.
// LDS 32KB: Ah | Al | Bh | Bl (512 granules of 16B each).
// ---------------------------------------------------------------------------
__global__ __launch_bounds__(256, 2) void dyn_conv_mfma(
    const unsigned short* __restrict__ Afh, const unsigned short* __restrict__ Afl,
    const unsigned short* __restrict__ xTh, const unsigned short* __restrict__ xTl,
    const float* __restrict__ bias_ws, float* __restrict__ out) {
  __shared__ bf16x8 lds[2048];           // 32 KB
  char* ldsb = (char*)lds;
  const int pt = blockIdx.x;             // px tile (128 px = 2 image rows)
  const int b = blockIdx.y;
  const int tid = threadIdx.x;
  const int l = tid & 63;
  const int wid = tid >> 6;
  const int wr = wid >> 1, wc = wid & 1; // wave tile: 64 fo x 64 px

  f32x4 acc[4][4] = {};

  for (int s = 0; s < 36; ++s) {
    const int t = s >> 2, fib = s & 3;
    const int dy = t / 3 - 1, dx = t % 3 - 1;
    __syncthreads();                     // previous tile fully consumed
    // ---- stage A (kern fragments, linear) : hi then lo
    {
      size_t abase = (size_t)b * KSZ + (size_t)(t * 4 + fib) * 4096;  // elems
#pragma unroll
      for (int r = 0; r < 2; ++r) {
        int g = tid + r * 256;
        GLOAD16(Afh + abase + (size_t)g * 8, ldsb + g * 16);
        GLOAD16(Afl + abase + (size_t)g * 8, ldsb + 8192 + g * 16);
      }
    }
    // ---- stage B (x slice, source-swizzled so ds_read_b128 is conflict-free)
    {
#pragma unroll
      for (int r = 0; r < 2; ++r) {
        int g = tid + r * 256;
        int px = g >> 2;
        int fq = (g & 3) ^ (px & 3);     // inverse swizzle on source
        int yy = 2 * pt + (px >> 6) + dy + 1;
        int xx = (px & 63) + dx + 1;
        size_t boff = ((size_t)b * XPAD * XPAD + (size_t)yy * XPAD + xx) * FIN_C +
                      fib * 32 + fq * 8;
        GLOAD16(xTh + boff, ldsb + 16384 + g * 16);
        GLOAD16(xTl + boff, ldsb + 24576 + g * 16);
      }
    }
    __syncthreads();                     // compiler drains vmcnt before barrier

    // ---- fragments + MFMA
    bf16x8 ah[4], al[4];
#pragma unroll
    for (int m = 0; m < 4; ++m) {
      ah[m] = lds[(wr * 4 + m) * 64 + l];
      al[m] = lds[512 + (wr * 4 + m) * 64 + l];
    }
    const int kq = l >> 4;
#pragma unroll
    for (int nn = 0; nn < 4; ++nn) {
      int px = wc * 64 + nn * 16 + (l & 15);
      int slot = px * 4 + (kq ^ (px & 3));
      bf16x8 bh = lds[1024 + slot];
      bf16x8 bl = lds[1536 + slot];
#pragma unroll
      for (int m = 0; m < 4; ++m) {
        acc[m][nn] = __builtin_amdgcn_mfma_f32_16x16x32_bf16(ah[m], bh, acc[m][nn], 0, 0, 0);
        acc[m][nn] = __builtin_amdgcn_mfma_f32_16x16x32_bf16(ah[m], bl, acc[m][nn], 0, 0, 0);
        acc[m][nn] = __builtin_amdgcn_mfma_f32_16x16x32_bf16(al[m], bh, acc[m][nn], 0, 0, 0);
      }
    }
  }

  // ---- epilogue: D col = lane&15 (px), row = (lane>>4)*4 + reg (fo)
  float bvv[4][4];
#pragma unroll
  for (int m = 0; m < 4; ++m)
#pragma unroll
    for (int r = 0; r < 4; ++r)
      bvv[m][r] = bias_ws[b * FOUT_C + wr * 64 + m * 16 + (l >> 4) * 4 + r];

#pragma unroll
  for (int m = 0; m < 4; ++m) {
#pragma unroll
    for (int nn = 0; nn < 4; ++nn) {
#pragma unroll
      for (int r = 0; r < 4; ++r) {
        int fo = wr * 64 + m * 16 + (l >> 4) * 4 + r;
        int p = pt * 128 + wc * 64 + nn * 16 + (l & 15);
        out[((size_t)b * FOUT_C + fo) * (HW * HW) + p] = acc[m][nn][r] + bvv[m][r];
      }
    }
  }
}

// ===========================================================================
// Fallback (Round-1 proven path) in case ws_size < WS_NEED
// ===========================================================================
__global__ __launch_bounds__(256) void hyper_gemm_fb(
    const float* __restrict__ lat, const float* __restrict__ W,
    const float* __restrict__ bvec, float* __restrict__ kt,
    float* __restrict__ bias_ws) {
  int d = blockIdx.x * 256 + threadIdx.x;
  if (d >= NROWS) return;
  long n; int fo; bool isBias = (d >= KSZ);
  if (!isBias) {
    fo = d & 127; int rest = d >> 7; int tap = rest % 9; int fi = rest / 9;
    n = (long)fo * (FIN_C * KK * KK) + fi * (KK * KK) + tap;
  } else { fo = d - KSZ; n = KSZ + fo; }
  const float* wrow = W + n * LATD;
  float bv = bvec[n];
  float acc[NB];
#pragma unroll
  for (int b = 0; b < NB; ++b) acc[b] = bv;
#pragma unroll 2
  for (int k = 0; k < LATD; k += 4) {
    float4 wv = *reinterpret_cast<const float4*>(wrow + k);
#pragma unroll
    for (int b = 0; b < NB; ++b) {
      acc[b] += wv.x * lat[b * LATD + k] + wv.y * lat[b * LATD + k + 1] +
                wv.z * lat[b * LATD + k + 2] + wv.w * lat[b * LATD + k + 3];
    }
  }
  if (!isBias) {
#pragma unroll
    for (int b = 0; b < NB; ++b) kt[(long)b * KSZ + d] = acc[b];
  } else {
#pragma unroll
    for (int b = 0; b < NB; ++b) bias_ws[b * FOUT_C + fo] = acc[b];
  }
}

__global__ __launch_bounds__(64) void dyn_conv_fb(
    const float* __restrict__ x, const float* __restrict__ kt,
    const float* __restrict__ bias_ws, float* __restrict__ out) {
  const int h = blockIdx.x, b = blockIdx.y, fo0 = blockIdx.z * 32;
  const int w = threadIdx.x;
  const float* xb = x + (long)b * FIN_C * (HW * HW);
  const float* ktb = kt + (long)b * KSZ;
  const float* bb = bias_ws + b * FOUT_C + fo0;
  float acc[32];
#pragma unroll
  for (int j = 0; j < 32; ++j) acc[j] = bb[j];
  for (int fi = 0; fi < FIN_C; ++fi) {
    float xv[9];
    const float* xr = xb + fi * (HW * HW);
#pragma unroll
    for (int ky = 0; ky < 3; ++ky) {
      int hy = h + ky - 1;
      bool vr = (hy >= 0) && (hy < HW);
      const float* row = xr + hy * HW;
      xv[ky * 3 + 0] = (vr && w > 0) ? row[w - 1] : 0.f;
      xv[ky * 3 + 1] = vr ? row[w] : 0.f;
      xv[ky * 3 + 2] = (vr && w < 63) ? row[w + 1] : 0.f;
    }
    const float* wt = ktb + fi * (KK * KK * FOUT_C) + fo0;
#pragma unroll
    for (int t = 0; t < 9; ++t)
#pragma unroll
      for (int j = 0; j < 32; ++j) acc[j] += xv[t] * wt[t * FOUT_C + j];
  }
  float* ob = out + (((long)b * FOUT_C + fo0) * HW + h) * HW + w;
#pragma unroll
  for (int j = 0; j < 32; ++j) ob[(long)j * (HW * HW)] = acc[j];
}

// ---------------------------------------------------------------------------
extern "C" void kernel_launch(void* const* d_in, const int* in_sizes, int n_in,
                              void* d_out, int out_size, void* d_ws, size_t ws_size,
                              hipStream_t stream) {
  const float* x   = (const float*)d_in[0];
  const float* lat = (const float*)d_in[1];
  const float* W   = (const float*)d_in[2];
  const float* bv  = (const float*)d_in[3];
  float* out = (float*)d_out;
  char* ws = (char*)d_ws;

  if (ws_size >= WS_NEED) {
    unsigned short* Afh = (unsigned short*)(ws + AFH_OFF);
    unsigned short* Afl = (unsigned short*)(ws + AFL_OFF);
    unsigned short* xTh = (unsigned short*)(ws + XTH_OFF);
    unsigned short* xTl = (unsigned short*)(ws + XTL_OFF);
    float* bias_ws = (float*)(ws + BIAS_OFF);

    hyper_gemm2<<<dim3(577), dim3(256), 0, stream>>>(lat, W, bv, Afh, Afl, bias_ws);
    prepass<<<dim3(XPAD, NB), dim3(256), 0, stream>>>(x, xTh, xTl);
    dyn_conv_mfma<<<dim3(32, NB), dim3(256), 0, stream>>>(Afh, Afl, xTh, xTl, bias_ws, out);
  } else {
    float* kt = (float*)d_ws;
    float* bias_ws = kt + (size_t)NB * KSZ;
    hyper_gemm_fb<<<dim3((NROWS + 255) / 256), dim3(256), 0, stream>>>(lat, W, bv, kt, bias_ws);
    dyn_conv_fb<<<dim3(HW, NB, 4), dim3(64), 0, stream>>>(x, kt, bias_ws, out);
  }
}